// Round 7
// baseline (982.221 us; speedup 1.0000x reference)
//
#include <hip/hip_runtime.h>
#include <stdint.h>
#include <math.h>

typedef unsigned short u16;
typedef short  s16x8 __attribute__((ext_vector_type(8)));
typedef float  f32x4 __attribute__((ext_vector_type(4)));

#define DEVI __device__ __forceinline__

DEVI float b2f(u16 u){ union{unsigned int i; float f;} v; v.i = ((unsigned int)u)<<16; return v.f; }
DEVI u16 f2b(float f){
  union{float f; unsigned int i;} v; v.f = f;
  unsigned int r = v.i + 0x7FFFu + ((v.i >> 16) & 1u);   // RNE
  return (u16)(r >> 16);
}

// ---------------------------------------------------------------------------
// GEMM: C[M,N] = A[M,K] @ Bt[N,K]^T   (A,Bt bf16, fp32 accum, fp32 bias)
// MODE 0: store bf16 | MODE 1: bias + exact GELU, store bf16
// MODE 2: resid_f32[M,N] += acc + bias  (SPLITK>1: atomicAdd, bias on z==0)
// 128x128 tile, BK=32, 4 waves (2x2), 16x16x32 bf16 MFMA.
// K-loop: 4-DEEP register prefetch (round-7). History:
//  r1: global_load_lds + vmcnt(0) drain regressed (kills cross-barrier pipe).
//  r4: splitk>2 regressed 2.2x (atomic RMW traffic super-linear in slices).
//  r6: BM=64 grid-doubling raised occupancy 11.5->24.9% but dur 46->51us —
//      latency-via-TLP FALSIFIED: the waitcnt-before-LDS-store stall is per-
//      iteration and lockstep across waves; slack = prefetch_depth x compute.
//  r7: depth 2->4 doubles slack (~800-1000cyc) to cover A-operand L3/HBM
//      latency. +~32 VGPR, fine at 2 blocks/CU.  niter % 4 == 0 required
//      (all call shapes satisfy; co moved to splitk=2).
// ---------------------------------------------------------------------------
template<int MODE, int SPLITK>
__launch_bounds__(256, 2)
__global__ void gemm_bt(const u16* __restrict__ A, const u16* __restrict__ Bt,
                        const float* __restrict__ bias, u16* __restrict__ outb,
                        float* __restrict__ resid, int M, int N, int K)
{
  __shared__ __align__(16) u16 lds_a[128*32];
  __shared__ __align__(16) u16 lds_b[128*32];
  const int tid = threadIdx.x;
  const int w = tid >> 6, l = tid & 63;
  const int q = l >> 4, r = l & 15;
  const int wm = w & 1, wn = w >> 1;
  const size_t m0 = (size_t)blockIdx.y * 128, n0 = (size_t)blockIdx.x * 128;
  const int kslice = K / SPLITK;
  const int kbeg = (SPLITK > 1) ? (int)blockIdx.z * kslice : 0;

  const int srow = tid >> 2;            // staging row 0..63
  const int scol = (tid & 3) * 8;       // staging col (u16) 0/8/16/24
  const u16* pa0 = A  + (m0 + srow)      * (size_t)K + kbeg + scol;
  const u16* pa1 = A  + (m0 + 64 + srow) * (size_t)K + kbeg + scol;
  const u16* pb0 = Bt + (n0 + srow)      * (size_t)K + kbeg + scol;
  const u16* pb1 = Bt + (n0 + 64 + srow) * (size_t)K + kbeg + scol;

  f32x4 acc[4][4];
  f32x4 zero = {0.f, 0.f, 0.f, 0.f};
#pragma unroll
  for (int i = 0; i < 4; i++)
#pragma unroll
    for (int j = 0; j < 4; j++) acc[i][j] = zero;

  auto compute = [&]() {
    s16x8 af[4], bfr[4];
#pragma unroll
    for (int mm = 0; mm < 4; mm++)
      af[mm] = *(const s16x8*)&lds_a[(wm*64 + mm*16 + r)*32 + q*8];
#pragma unroll
    for (int nn = 0; nn < 4; nn++)
      bfr[nn] = *(const s16x8*)&lds_b[(wn*64 + nn*16 + r)*32 + q*8];
#pragma unroll
    for (int mm = 0; mm < 4; mm++)
#pragma unroll
      for (int nn = 0; nn < 4; nn++)
        acc[mm][nn] = __builtin_amdgcn_mfma_f32_16x16x32_bf16(af[mm], bfr[nn], acc[mm][nn], 0, 0, 0);
  };

  // four register buffer sets (tiles t..t+3), 4-deep prefetch pipeline
  s16x8 a0_0 = *(const s16x8*)(pa0);
  s16x8 a1_0 = *(const s16x8*)(pa1);
  s16x8 b0_0 = *(const s16x8*)(pb0);
  s16x8 b1_0 = *(const s16x8*)(pb1);
  s16x8 a0_1 = *(const s16x8*)(pa0 + 32);
  s16x8 a1_1 = *(const s16x8*)(pa1 + 32);
  s16x8 b0_1 = *(const s16x8*)(pb0 + 32);
  s16x8 b1_1 = *(const s16x8*)(pb1 + 32);
  s16x8 a0_2 = *(const s16x8*)(pa0 + 64);
  s16x8 a1_2 = *(const s16x8*)(pa1 + 64);
  s16x8 b0_2 = *(const s16x8*)(pb0 + 64);
  s16x8 b1_2 = *(const s16x8*)(pb1 + 64);
  s16x8 a0_3 = *(const s16x8*)(pa0 + 96);
  s16x8 a1_3 = *(const s16x8*)(pa1 + 96);
  s16x8 b0_3 = *(const s16x8*)(pb0 + 96);
  s16x8 b1_3 = *(const s16x8*)(pb1 + 96);

  const int niter = kslice / 32;         // multiple of 4 by construction
  for (int it = 0; it < niter; it += 4){
    // ---- slot 0 (buffer 0, tile it) ----
    __syncthreads();
    *(s16x8*)&lds_a[srow*32 + scol]        = a0_0;
    *(s16x8*)&lds_a[(64 + srow)*32 + scol] = a1_0;
    *(s16x8*)&lds_b[srow*32 + scol]        = b0_0;
    *(s16x8*)&lds_b[(64 + srow)*32 + scol] = b1_0;
    __syncthreads();
    if (it + 4 < niter){
      int k4 = (it + 4) * 32;
      a0_0 = *(const s16x8*)(pa0 + k4);
      a1_0 = *(const s16x8*)(pa1 + k4);
      b0_0 = *(const s16x8*)(pb0 + k4);
      b1_0 = *(const s16x8*)(pb1 + k4);
    }
    compute();
    // ---- slot 1 (buffer 1, tile it+1) ----
    __syncthreads();
    *(s16x8*)&lds_a[srow*32 + scol]        = a0_1;
    *(s16x8*)&lds_a[(64 + srow)*32 + scol] = a1_1;
    *(s16x8*)&lds_b[srow*32 + scol]        = b0_1;
    *(s16x8*)&lds_b[(64 + srow)*32 + scol] = b1_1;
    __syncthreads();
    if (it + 5 < niter){
      int k5 = (it + 5) * 32;
      a0_1 = *(const s16x8*)(pa0 + k5);
      a1_1 = *(const s16x8*)(pa1 + k5);
      b0_1 = *(const s16x8*)(pb0 + k5);
      b1_1 = *(const s16x8*)(pb1 + k5);
    }
    compute();
    // ---- slot 2 (buffer 2, tile it+2) ----
    __syncthreads();
    *(s16x8*)&lds_a[srow*32 + scol]        = a0_2;
    *(s16x8*)&lds_a[(64 + srow)*32 + scol] = a1_2;
    *(s16x8*)&lds_b[srow*32 + scol]        = b0_2;
    *(s16x8*)&lds_b[(64 + srow)*32 + scol] = b1_2;
    __syncthreads();
    if (it + 6 < niter){
      int k6 = (it + 6) * 32;
      a0_2 = *(const s16x8*)(pa0 + k6);
      a1_2 = *(const s16x8*)(pa1 + k6);
      b0_2 = *(const s16x8*)(pb0 + k6);
      b1_2 = *(const s16x8*)(pb1 + k6);
    }
    compute();
    // ---- slot 3 (buffer 3, tile it+3) ----
    __syncthreads();
    *(s16x8*)&lds_a[srow*32 + scol]        = a0_3;
    *(s16x8*)&lds_a[(64 + srow)*32 + scol] = a1_3;
    *(s16x8*)&lds_b[srow*32 + scol]        = b0_3;
    *(s16x8*)&lds_b[(64 + srow)*32 + scol] = b1_3;
    __syncthreads();
    if (it + 7 < niter){
      int k7 = (it + 7) * 32;
      a0_3 = *(const s16x8*)(pa0 + k7);
      a1_3 = *(const s16x8*)(pa1 + k7);
      b0_3 = *(const s16x8*)(pb0 + k7);
      b1_3 = *(const s16x8*)(pb1 + k7);
    }
    compute();
  }

  // C/D layout: row = q*4+j, col = r  [m89/m91]
#pragma unroll
  for (int nn = 0; nn < 4; nn++){
    size_t col = n0 + wn*64 + nn*16 + r;
    float bv = 0.0f;
    if (MODE != 0 && (SPLITK == 1 || blockIdx.z == 0)) bv = bias[col];
#pragma unroll
    for (int mm = 0; mm < 4; mm++){
#pragma unroll
      for (int j = 0; j < 4; j++){
        size_t row = m0 + wm*64 + mm*16 + q*4 + j;
        float v = acc[mm][nn][j] + bv;
        if (MODE == 1) v = 0.5f * v * (1.0f + erff(v * 0.70710678118654752f));
        if (MODE == 2){
          if (SPLITK > 1) atomicAdd(&resid[row * N + col], v);
          else            resid[row * N + col] += v;
        } else {
          outb[row * N + col] = f2b(v);
        }
      }
    }
  }
}

// ---------------------------------------------------------------------------
// Zero-sink attention (flash-style). grid=(Nq/64, H, B), block=256 (4 waves).
// V comes PRE-TRANSPOSED in global: vT[b][768][Nkv] (head h at rows h*64..).
// KVBLK=64: K tile [64][64] and Vt tile [64][64], BOTH with xor-chunk swizzle
// applied on the GLOBAL side (linear b128 LDS stores = conflict-free; swizzled
// b128 reads = 2-way max).
// SOFTMAX WITHOUT MAX-TRACKING (round-3): softmax is shift-invariant and the
// zero-sink pins the reference shift at 0; logits here are tiny (LN'd acts x
// 0.02-scale weights -> |s| < ~5, fp32 exp overflows only past 88), so
// p = exp(s) directly. Row-sum l via MFMA with a ones B-fragment.
// ---------------------------------------------------------------------------
__launch_bounds__(256, 4)
__global__ void attn_zero_kernel(const u16* __restrict__ Qp, const u16* __restrict__ Kp,
                                 const u16* __restrict__ vT, u16* __restrict__ Op,
                                 int Nq, int Nkv, int LDq, int LDk,
                                 float outw, int accumulate)
{
  __shared__ __align__(16) u16 lds_k[64*64];        // [kv][d], chunk-swizzled
  __shared__ __align__(16) u16 lds_v[64*64];        // [d][kv], chunk-swizzled
  __shared__ __align__(16) u16 lds_p[4][2][16*40];  // per-wave P halves, pitch 40

  const int tid = threadIdx.x;
  const int w = tid >> 6, l = tid & 63;
  const int q = l >> 4, r = l & 15;
  const int h = blockIdx.y, b = blockIdx.z;
  const int q0 = blockIdx.x * 64 + w * 16;

  s16x8 qf[2];
  {
    const u16* qrow = Qp + (size_t)(b*Nq + q0 + r) * LDq + h*64;
    qf[0] = *(const s16x8*)(qrow + q*8);
    qf[1] = *(const s16x8*)(qrow + 32 + q*8);
  }

  f32x4 o[4];
  f32x4 lsum;
  f32x4 zero = {0.f, 0.f, 0.f, 0.f};
#pragma unroll
  for (int nn = 0; nn < 4; nn++) o[nn] = zero;
  lsum = zero;
  const s16x8 ones = {(short)0x3F80, (short)0x3F80, (short)0x3F80, (short)0x3F80,
                      (short)0x3F80, (short)0x3F80, (short)0x3F80, (short)0x3F80}; // bf16 1.0
  const float C2 = 0.18033688011112042f;   // 0.125 * log2(e): exp(s*0.125) = exp2(s*C2)

  // staging: chunk c -> row=c>>3, slot-chunk cc=c&7, global-chunk cc^(row&7).
  // thread stages chunks {tid, 256+tid} (rows 0..31, 32..63; (row+32)&7==row&7).
  const int crow = tid >> 3;
  const int ccol = ((tid & 7) ^ (crow & 7)) << 3;
  const u16* Kbase = Kp + (size_t)b * Nkv * LDk + h*64;
  const u16* gk = Kbase + (size_t)crow * LDk + ccol;
  const u16* Vbase = vT + ((size_t)b * 768 + h*64) * (size_t)Nkv;
  const u16* gv = Vbase + (size_t)crow * Nkv + ccol;
  const size_t gk32 = (size_t)32 * LDk;   // +32 kv rows (K)
  const size_t gv32 = (size_t)32 * Nkv;   // +32 d rows (Vt)

  // prefetch tile 0
  s16x8 kr0 = *(const s16x8*)(gk);
  s16x8 kr1 = *(const s16x8*)(gk + gk32);
  s16x8 vr0 = *(const s16x8*)(gv);
  s16x8 vr1 = *(const s16x8*)(gv + gv32);

  for (int kv0 = 0; kv0 < Nkv; kv0 += 64){
    __syncthreads();
    *(s16x8*)&lds_k[tid * 8]         = kr0;   // contiguous b128 stores
    *(s16x8*)&lds_k[(256 + tid) * 8] = kr1;
    *(s16x8*)&lds_v[tid * 8]         = vr0;
    *(s16x8*)&lds_v[(256 + tid) * 8] = vr1;
    __syncthreads();
    if (kv0 + 64 < Nkv){                  // issue next tile's loads (no wait)
      const u16* gkn = gk + (size_t)(kv0 + 64) * LDk;
      kr0 = *(const s16x8*)(gkn);
      kr1 = *(const s16x8*)(gkn + gk32);
      vr0 = *(const s16x8*)(gv + (kv0 + 64));
      vr1 = *(const s16x8*)(gv + (kv0 + 64) + gv32);
    }

    // S = Q K^T (raw logits; 0.125 scale folded into exp2 constant)
    f32x4 s[4];
#pragma unroll
    for (int kk = 0; kk < 4; kk++){
      int row = kk*16 + r;
      s16x8 kf0 = *(const s16x8*)&lds_k[row*64 + ((q       ^ (row & 7)) << 3)];
      s16x8 kf1 = *(const s16x8*)&lds_k[row*64 + (((4 + q) ^ (row & 7)) << 3)];
      f32x4 t = zero;
      t = __builtin_amdgcn_mfma_f32_16x16x32_bf16(qf[0], kf0, t, 0, 0, 0);
      t = __builtin_amdgcn_mfma_f32_16x16x32_bf16(qf[1], kf1, t, 0, 0, 0);
      s[kk] = t;
    }

    // P = exp(s/8), straight to bf16 (no max-tracking, no rescale)
    u16* P0 = &lds_p[w][0][0];
    u16* P1 = &lds_p[w][1][0];
#pragma unroll
    for (int j = 0; j < 4; j++){
      P0[(q*4 + j)*40 + r]      = f2b(exp2f(s[0][j] * C2));
      P0[(q*4 + j)*40 + 16 + r] = f2b(exp2f(s[1][j] * C2));
      P1[(q*4 + j)*40 + r]      = f2b(exp2f(s[2][j] * C2));
      P1[(q*4 + j)*40 + 16 + r] = f2b(exp2f(s[3][j] * C2));
    }
    s16x8 pf0 = *(const s16x8*)&P0[r*40 + q*8];
    s16x8 pf1 = *(const s16x8*)&P1[r*40 + q*8];
#pragma unroll
    for (int nn = 0; nn < 4; nn++){
      int row = nn*16 + r;                   // d index (B-fragment n)
      s16x8 vf0 = *(const s16x8*)&lds_v[row*64 + ((q       ^ (row & 7)) << 3)];
      s16x8 vf1 = *(const s16x8*)&lds_v[row*64 + (((4 + q) ^ (row & 7)) << 3)];
      o[nn] = __builtin_amdgcn_mfma_f32_16x16x32_bf16(pf0, vf0, o[nn], 0, 0, 0);
      o[nn] = __builtin_amdgcn_mfma_f32_16x16x32_bf16(pf1, vf1, o[nn], 0, 0, 0);
    }
    // row-sum of P via ones-B MFMA (C layout row=q*4+j, col=r; cols identical)
    lsum = __builtin_amdgcn_mfma_f32_16x16x32_bf16(pf0, ones, lsum, 0, 0, 0);
    lsum = __builtin_amdgcn_mfma_f32_16x16x32_bf16(pf1, ones, lsum, 0, 0, 0);
  }

#pragma unroll
  for (int j = 0; j < 4; j++){
    float inv = outw / (1.0f + lsum[j]);     // sink contributes exp(0)=1
    size_t rowoff = (size_t)(b*Nq + q0 + q*4 + j) * 768 + h*64;
#pragma unroll
    for (int nn = 0; nn < 4; nn++){
      float v = o[nn][j] * inv;
      size_t idx = rowoff + nn*16 + r;
      if (accumulate) v += b2f(Op[idx]);
      Op[idx] = f2b(v);
    }
  }
}

// ---------------------------------------------------------------------------
// LayerNorm over D=768 fp32 rows -> bf16 out. One block (256) per row.
// ---------------------------------------------------------------------------
__launch_bounds__(256)
__global__ void ln_kernel(const float* __restrict__ x, const float* __restrict__ g,
                          const float* __restrict__ bta, u16* __restrict__ out)
{
  __shared__ float red[8];
  const size_t row = blockIdx.x;
  const float* xr = x + row * 768;
  int t = threadIdx.x;
  float v0 = xr[t], v1 = xr[t + 256], v2 = xr[t + 512];
  float s  = v0 + v1 + v2;
  float s2 = v0*v0 + v1*v1 + v2*v2;
#pragma unroll
  for (int d = 1; d < 64; d <<= 1){ s += __shfl_xor(s, d); s2 += __shfl_xor(s2, d); }
  int w = t >> 6;
  if ((t & 63) == 0){ red[w] = s; red[4 + w] = s2; }
  __syncthreads();
  s  = red[0] + red[1] + red[2] + red[3];
  s2 = red[4] + red[5] + red[6] + red[7];
  float mean = s * (1.0f / 768.0f);
  float var  = s2 * (1.0f / 768.0f) - mean * mean;
  float rstd = rsqrtf(var + 1e-5f);
  u16* orow = out + row * 768;
  orow[t]       = f2b((v0 - mean) * rstd * g[t]       + bta[t]);
  orow[t + 256] = f2b((v1 - mean) * rstd * g[t + 256] + bta[t + 256]);
  orow[t + 512] = f2b((v2 - mean) * rstd * g[t + 512] + bta[t + 512]);
}

// fp32 -> bf16 transpose (R x C -> C x R), dims multiples of 64. block (64,4).
__global__ void transpose_kernel(const float* __restrict__ in, u16* __restrict__ out, int R, int C)
{
  __shared__ u16 tile[64][65];
  int c0 = blockIdx.x * 64, r0 = blockIdx.y * 64;
  for (int i = threadIdx.y; i < 64; i += 4)
    tile[i][threadIdx.x] = f2b(in[(size_t)(r0 + i) * C + c0 + threadIdx.x]);
  __syncthreads();
  for (int i = threadIdx.y; i < 64; i += 4)
    out[(size_t)(c0 + i) * R + r0 + threadIdx.x] = tile[threadIdx.x][i];
}

// batched u16 transpose for V: in = per-batch [N][LD] slab at col offset coff,
// out = [b][768][N]. grid (768/64, N/64, B), block (64,4).
__global__ void transpose_v_kernel(const u16* __restrict__ in, u16* __restrict__ out,
                                   int N, int LD, int coff)
{
  __shared__ u16 tile[64][65];
  int bz = blockIdx.z;
  int c0 = blockIdx.x * 64, n0 = blockIdx.y * 64;
  const u16* ib = in + ((size_t)bz * N + n0) * LD + coff + c0;
  for (int i = threadIdx.y; i < 64; i += 4)
    tile[i][threadIdx.x] = ib[(size_t)i * LD + threadIdx.x];     // token n0+i, chan c0+tx
  __syncthreads();
  u16* ob = out + ((size_t)bz * 768 + c0) * N + n0;
  for (int i = threadIdx.y; i < 64; i += 4)
    ob[(size_t)i * N + threadIdx.x] = tile[threadIdx.x][i];      // chan c0+i, token n0+tx
}

// fp32 vectorized copy (n multiple of 4).
__global__ void copy_f32(const float* __restrict__ in, float* __restrict__ out, long n4){
  long i = (long)blockIdx.x * blockDim.x + threadIdx.x;
  long stride = (long)gridDim.x * blockDim.x;
  const f32x4* in4 = (const f32x4*)in;
  f32x4* out4 = (f32x4*)out;
  for (; i < n4; i += stride) out4[i] = in4[i];
}

// ---------------------------------------------------------------------------
extern "C" void kernel_launch(void* const* d_in, const int* in_sizes, int n_in,
                              void* d_out, int out_size, void* d_ws, size_t ws_size,
                              hipStream_t stream)
{
  const int B = 4, NI = 1024, NC = 256, D = 768, FF = 3072, H = 12, L = 2;
  const int RI = B * NI;   // 4096 img rows
  const int RC = B * NC;   // 1024 clinic rows

  const float* img    = (const float*)d_in[0];
  const float* clinic = (const float*)d_in[1];
  const float* ln1_g  = (const float*)d_in[2];
  const float* ln1_b  = (const float*)d_in[3];
  const float* w_qkv  = (const float*)d_in[4];
  const float* w_o    = (const float*)d_in[5];
  const float* b_o    = (const float*)d_in[6];
  const float* ln2_g  = (const float*)d_in[7];
  const float* ln2_b  = (const float*)d_in[8];
  const float* w_ff1  = (const float*)d_in[9];
  const float* b_ff1  = (const float*)d_in[10];
  const float* w_ff2  = (const float*)d_in[11];
  const float* b_ff2  = (const float*)d_in[12];
  const float* cn_i_g = (const float*)d_in[13];
  const float* cn_i_b = (const float*)d_in[14];
  const float* cn_c_g = (const float*)d_in[15];
  const float* cn_c_b = (const float*)d_in[16];
  const float* w_iq   = (const float*)d_in[17];
  const float* w_ik   = (const float*)d_in[18];
  const float* w_iv   = (const float*)d_in[19];
  const float* w_cq   = (const float*)d_in[20];
  const float* w_ck   = (const float*)d_in[21];
  const float* w_cv   = (const float*)d_in[22];
  const float* w_io   = (const float*)d_in[23];
  const float* b_io   = (const float*)d_in[24];
  const float* w_co   = (const float*)d_in[25];
  const float* b_co   = (const float*)d_in[26];
  const float* fn_i_g = (const float*)d_in[27];
  const float* fn_i_b = (const float*)d_in[28];
  const float* fn_c_g = (const float*)d_in[29];
  const float* fn_c_b = (const float*)d_in[30];
  const float* iff_w1 = (const float*)d_in[31];
  const float* iff_b1 = (const float*)d_in[32];
  const float* iff_w2 = (const float*)d_in[33];
  const float* iff_b2 = (const float*)d_in[34];
  const float* cff_w1 = (const float*)d_in[35];
  const float* cff_b1 = (const float*)d_in[36];
  const float* cff_w2 = (const float*)d_in[37];
  const float* cff_b2 = (const float*)d_in[38];

  // ---- workspace carve (~121 MB) ----
  char* ws = (char*)d_ws;
  size_t off = 0;
  auto alloc = [&](size_t elems, size_t esz) -> void* {
    void* p = ws + off;
    off += ((elems * esz) + 255) & ~(size_t)255;
    return p;
  };
  u16* wqkvT[2]; u16* woT[2]; u16* ff1T[2]; u16* ff2T[2];
  for (int i = 0; i < 2; i++) wqkvT[i] = (u16*)alloc((size_t)3*D*D, 2);
  for (int i = 0; i < 2; i++) woT[i]   = (u16*)alloc((size_t)D*D, 2);
  for (int i = 0; i < 2; i++) ff1T[i]  = (u16*)alloc((size_t)FF*D, 2);
  for (int i = 0; i < 2; i++) ff2T[i]  = (u16*)alloc((size_t)D*FF, 2);
  u16* wiqkvT = (u16*)alloc((size_t)3*D*D, 2);   // fused [iq|ik|iv] as [2304][768]
  u16* wcqkvT = (u16*)alloc((size_t)3*D*D, 2);   // fused [cq|ck|cv]
  u16* wioT = (u16*)alloc((size_t)D*D, 2); u16* wcoT = (u16*)alloc((size_t)D*D, 2);
  u16* iff1T = (u16*)alloc((size_t)FF*D, 2); u16* iff2T = (u16*)alloc((size_t)D*FF, 2);
  u16* cff1T = (u16*)alloc((size_t)FF*D, 2); u16* cff2T = (u16*)alloc((size_t)D*FF, 2);

  float* img_f = (float*)alloc((size_t)RI*D, 4);   // fp32 residual streams
  float* cli_f = (float*)alloc((size_t)RC*D, 4);
  u16* xn_i = (u16*)alloc((size_t)RI*D, 2);
  u16* xn_c = (u16*)alloc((size_t)RC*D, 2);
  // shared region: {qkvb | cqkv} (projections) or {h1} (FFN hidden)
  u16* region = (u16*)alloc((size_t)RI*FF, 2);   // RI*FF > RI*3D + RC*3D
  u16* qkvb = region;
  u16* cqkv = region + (size_t)RI*3*D;
  u16* h1   = region;
  u16* ao_i = (u16*)alloc((size_t)RI*D, 2);      // attention outputs (bf16)
  u16* ao_c = (u16*)alloc((size_t)RC*D, 2);
  u16* vT_i = (u16*)alloc((size_t)B*D*NI, 2);    // pre-transposed V, img stream
  u16* vT_c = (u16*)alloc((size_t)B*D*NC, 2);    // pre-transposed V, clinic stream
  (void)ws_size; (void)in_sizes; (void)n_in; (void)out_size;

  auto T = [&](const float* in_, u16* out_, int R, int C){
    transpose_kernel<<<dim3(C/64, R/64), dim3(64, 4), 0, stream>>>(in_, out_, R, C);
  };
  auto TV = [&](const u16* in_, u16* out_, int N, int LD, int coff){
    transpose_v_kernel<<<dim3(D/64, N/64, B), dim3(64, 4), 0, stream>>>(in_, out_, N, LD, coff);
  };
  auto G0 = [&](const u16* A, const u16* Bt, u16* out_, int M, int N, int K){
    gemm_bt<0,1><<<dim3(N/128, M/128), 256, 0, stream>>>(A, Bt, nullptr, out_, nullptr, M, N, K);
  };
  auto G1 = [&](const u16* A, const u16* Bt, const float* bias, u16* out_, int M, int N, int K){
    gemm_bt<1,1><<<dim3(N/128, M/128), 256, 0, stream>>>(A, Bt, bias, out_, nullptr, M, N, K);
  };
  auto G2 = [&](const u16* A, const u16* Bt, const float* bias, float* resid, int M, int N, int K, int splitk){
    if (splitk == 2)
      gemm_bt<2,2><<<dim3(N/128, M/128, 2), 256, 0, stream>>>(A, Bt, bias, nullptr, resid, M, N, K);
    else
      gemm_bt<2,1><<<dim3(N/128, M/128, 1), 256, 0, stream>>>(A, Bt, bias, nullptr, resid, M, N, K);
  };
  auto ATT = [&](const u16* Q, const u16* K_, const u16* vTp, u16* O,
                 int Nq, int Nkv, int LDq, int LDk, float w_, int acc_){
    attn_zero_kernel<<<dim3(Nq/64, H, B), 256, 0, stream>>>(Q, K_, vTp, O, Nq, Nkv, LDq, LDk, w_, acc_);
  };
  auto CP = [&](const float* in_, float* out_, long n){
    copy_f32<<<1024, 256, 0, stream>>>(in_, out_, n / 4);
  };

  // ---- weight pre-transposes (K x N fp32 -> N x K bf16) ----
  for (int li = 0; li < L; li++){
    T(w_qkv + (size_t)li*D*3*D, wqkvT[li], D, 3*D);
    T(w_o   + (size_t)li*D*D,   woT[li],   D, D);
    T(w_ff1 + (size_t)li*D*FF,  ff1T[li],  D, FF);
    T(w_ff2 + (size_t)li*FF*D,  ff2T[li],  FF, D);
  }
  T(w_iq, wiqkvT,              D, D);
  T(w_ik, wiqkvT + (size_t)D*D,   D, D);
  T(w_iv, wiqkvT + (size_t)2*D*D, D, D);
  T(w_cq, wcqkvT,              D, D);
  T(w_ck, wcqkvT + (size_t)D*D,   D, D);
  T(w_cv, wcqkvT + (size_t)2*D*D, D, D);
  T(w_io, wioT, D, D); T(w_co, wcoT, D, D);
  T(iff_w1, iff1T, D, FF); T(iff_w2, iff2T, FF, D);
  T(cff_w1, cff1T, D, FF); T(cff_w2, cff2T, FF, D);

  // ---- fp32 residual streams ----
  CP(img,    img_f, (long)RI*D);
  CP(clinic, cli_f, (long)RC*D);

  // ---- transformer stack ----
  for (int li = 0; li < L; li++){
    ln_kernel<<<RI, 256, 0, stream>>>(img_f, ln1_g + li*D, ln1_b + li*D, xn_i);
    G0(xn_i, wqkvT[li], qkvb, RI, 3*D, D);
    TV(qkvb, vT_i, NI, 3*D, 2*D);                      // V slice -> [b][768][NI]
    ATT(qkvb, qkvb + D, vT_i, ao_i, NI, NI, 3*D, 3*D, 1.0f, 0);
    G2(ao_i, woT[li], b_o + li*D, img_f, RI, D, D, 2);
    ln_kernel<<<RI, 256, 0, stream>>>(img_f, ln2_g + li*D, ln2_b + li*D, xn_i);
    G1(xn_i, ff1T[li], b_ff1 + li*FF, h1, RI, FF, D);
    G2(h1, ff2T[li], b_ff2 + li*D, img_f, RI, D, FF, 2);
  }

  // ---- cross block ----
  ln_kernel<<<RI, 256, 0, stream>>>(img_f, cn_i_g, cn_i_b, xn_i);
  ln_kernel<<<RC, 256, 0, stream>>>(cli_f, cn_c_g, cn_c_b, xn_c);
  u16* iqkv = qkvb;   // [RI][3D]: iq | ik | iv
  u16* cqk  = cqkv;   // [RC][3D]: cq | ck | cv
  G0(xn_i, wiqkvT, iqkv, RI, 3*D, D);
  G0(xn_c, wcqkvT, cqk,  RC, 3*D, D);
  TV(iqkv, vT_i, NI, 3*D, 2*D);
  TV(cqk,  vT_c, NC, 3*D, 2*D);

  ATT(iqkv, cqk + D,  vT_c, ao_i, NI, NC, 3*D, 3*D, 0.5f, 0);
  ATT(iqkv, iqkv + D, vT_i, ao_i, NI, NI, 3*D, 3*D, 0.5f, 1);
  ATT(cqk,  iqkv + D, vT_i, ao_c, NC, NI, 3*D, 3*D, 0.5f, 0);
  ATT(cqk,  cqk + D,  vT_c, ao_c, NC, NC, 3*D, 3*D, 0.5f, 1);

  G2(ao_i, wioT, b_io, img_f, RI, D, D, 2);
  G2(ao_c, wcoT, b_co, cli_f, RC, D, D, 2);   // sk 4->2: niter%4, less atomic traffic

  ln_kernel<<<RI, 256, 0, stream>>>(img_f, fn_i_g, fn_i_b, xn_i);
  G1(xn_i, iff1T, iff_b1, h1, RI, FF, D);
  G2(h1, iff2T, iff_b2, img_f, RI, D, FF, 2);

  ln_kernel<<<RC, 256, 0, stream>>>(cli_f, fn_c_g, fn_c_b, xn_c);
  G1(xn_c, cff1T, cff_b1, h1, RC, FF, D);
  G2(h1, cff2T, cff_b2, cli_f, RC, D, FF, 2);  // sk 4->2 (niter%4==0: 48/4)

  // ---- emit fp32 outputs (img then clinic, flat) ----
  CP(img_f, (float*)d_out,                (long)RI*D);
  CP(cli_f, (float*)d_out + (size_t)RI*D, (long)RC*D);
}

// Round 8
// 952.207 us; speedup vs baseline: 1.0315x; 1.0315x over previous
//
#include <hip/hip_runtime.h>
#include <stdint.h>
#include <math.h>

typedef unsigned short u16;
typedef short  s16x8 __attribute__((ext_vector_type(8)));
typedef float  f32x4 __attribute__((ext_vector_type(4)));

#define DEVI __device__ __forceinline__

DEVI float b2f(u16 u){ union{unsigned int i; float f;} v; v.i = ((unsigned int)u)<<16; return v.f; }
DEVI u16 f2b(float f){
  union{float f; unsigned int i;} v; v.f = f;
  unsigned int r = v.i + 0x7FFFu + ((v.i >> 16) & 1u);   // RNE
  return (u16)(r >> 16);
}

// ---------------------------------------------------------------------------
// GEMM: C[M,N] = A[M,K] @ Bt[N,K]^T   (A,Bt bf16, fp32 accum, fp32 bias)
// MODE 0: store bf16 | MODE 1: bias + exact GELU, store bf16
// MODE 2: resid_f32[M,N] += acc + bias  (SPLITK>1: atomicAdd, bias on z==0)
// 128x128 tile, BK=32, 4 waves (2x2), 16x16x32 bf16 MFMA, 2-deep reg prefetch.
// History: r1 gload_lds+drain regressed; r4 splitk>2 regressed (atomic RMW);
// r6 BM=64 TLP regressed (latency is lockstep-per-iteration, not hidable);
// r7 4-deep prefetch regressed (codegen: VALU 6.6->23%) BUT showed FETCH
// 86->30MB possible => bytes not binding; load LATENCY is. r8: XCD-aware
// swizzle (T1) so each XCD's L2 owns a contiguous tile chunk (all B-panels +
// few A-panels fit 4MB) => loads hit local L2 (~200cyc) instead of L3/HBM
// (~900cyc), shrinking the per-iteration waitcnt stall. Requires per-slice
// nwg%8==0 (all call grids satisfy; z-offset preserves parity).
// niter must be EVEN (all call shapes satisfy).
// ---------------------------------------------------------------------------
template<int MODE, int SPLITK>
__launch_bounds__(256, 2)
__global__ void gemm_bt(const u16* __restrict__ A, const u16* __restrict__ Bt,
                        const float* __restrict__ bias, u16* __restrict__ outb,
                        float* __restrict__ resid, int M, int N, int K)
{
  __shared__ __align__(16) u16 lds_a[128*32];
  __shared__ __align__(16) u16 lds_b[128*32];
  const int tid = threadIdx.x;
  const int w = tid >> 6, l = tid & 63;
  const int q = l >> 4, r = l & 15;
  const int wm = w & 1, wn = w >> 1;

  // XCD-aware tile remap: hw XCD ~ linear_bid % 8; give XCD k the contiguous
  // tile range [k*q8,(k+1)*q8) in row-major (x fastest) order.
  int bx = blockIdx.x, by = blockIdx.y;
  {
    const int nwg = gridDim.x * gridDim.y;      // per z-slice; %8==0 for all calls
    const int bid = by * gridDim.x + bx;
    const int q8 = nwg >> 3;
    const int t = (bid & 7) * q8 + (bid >> 3);
    bx = t % gridDim.x;
    by = t / gridDim.x;
  }
  const size_t m0 = (size_t)by * 128, n0 = (size_t)bx * 128;
  const int kslice = K / SPLITK;
  const int kbeg = (SPLITK > 1) ? (int)blockIdx.z * kslice : 0;

  const int srow = tid >> 2;            // staging row 0..63
  const int scol = (tid & 3) * 8;       // staging col (u16) 0/8/16/24
  const u16* pa0 = A  + (m0 + srow)      * (size_t)K + kbeg + scol;
  const u16* pa1 = A  + (m0 + 64 + srow) * (size_t)K + kbeg + scol;
  const u16* pb0 = Bt + (n0 + srow)      * (size_t)K + kbeg + scol;
  const u16* pb1 = Bt + (n0 + 64 + srow) * (size_t)K + kbeg + scol;

  f32x4 acc[4][4];
  f32x4 zero = {0.f, 0.f, 0.f, 0.f};
#pragma unroll
  for (int i = 0; i < 4; i++)
#pragma unroll
    for (int j = 0; j < 4; j++) acc[i][j] = zero;

  auto compute = [&]() {
    s16x8 af[4], bfr[4];
#pragma unroll
    for (int mm = 0; mm < 4; mm++)
      af[mm] = *(const s16x8*)&lds_a[(wm*64 + mm*16 + r)*32 + q*8];
#pragma unroll
    for (int nn = 0; nn < 4; nn++)
      bfr[nn] = *(const s16x8*)&lds_b[(wn*64 + nn*16 + r)*32 + q*8];
#pragma unroll
    for (int mm = 0; mm < 4; mm++)
#pragma unroll
      for (int nn = 0; nn < 4; nn++)
        acc[mm][nn] = __builtin_amdgcn_mfma_f32_16x16x32_bf16(af[mm], bfr[nn], acc[mm][nn], 0, 0, 0);
  };

  // two register buffers (tiles t and t+1), 2-deep prefetch pipeline
  s16x8 a0_0 = *(const s16x8*)(pa0);
  s16x8 a1_0 = *(const s16x8*)(pa1);
  s16x8 b0_0 = *(const s16x8*)(pb0);
  s16x8 b1_0 = *(const s16x8*)(pb1);
  s16x8 a0_1 = *(const s16x8*)(pa0 + 32);
  s16x8 a1_1 = *(const s16x8*)(pa1 + 32);
  s16x8 b0_1 = *(const s16x8*)(pb0 + 32);
  s16x8 b1_1 = *(const s16x8*)(pb1 + 32);

  const int niter = kslice / 32;         // even by construction
  for (int it = 0; it < niter; it += 2){
    // ---- even tile (buffer 0) ----
    __syncthreads();                      // prior compute's LDS reads done
    *(s16x8*)&lds_a[srow*32 + scol]        = a0_0;
    *(s16x8*)&lds_a[(64 + srow)*32 + scol] = a1_0;
    *(s16x8*)&lds_b[srow*32 + scol]        = b0_0;
    *(s16x8*)&lds_b[(64 + srow)*32 + scol] = b1_0;
    __syncthreads();                      // tile visible
    if (it + 2 < niter){                  // issue loads for tile it+2 (no wait)
      int k2 = (it + 2) * 32;
      a0_0 = *(const s16x8*)(pa0 + k2);
      a1_0 = *(const s16x8*)(pa1 + k2);
      b0_0 = *(const s16x8*)(pb0 + k2);
      b1_0 = *(const s16x8*)(pb1 + k2);
    }
    compute();
    // ---- odd tile (buffer 1) ----
    __syncthreads();
    *(s16x8*)&lds_a[srow*32 + scol]        = a0_1;
    *(s16x8*)&lds_a[(64 + srow)*32 + scol] = a1_1;
    *(s16x8*)&lds_b[srow*32 + scol]        = b0_1;
    *(s16x8*)&lds_b[(64 + srow)*32 + scol] = b1_1;
    __syncthreads();
    if (it + 3 < niter){                  // issue loads for tile it+3
      int k3 = (it + 3) * 32;
      a0_1 = *(const s16x8*)(pa0 + k3);
      a1_1 = *(const s16x8*)(pa1 + k3);
      b0_1 = *(const s16x8*)(pb0 + k3);
      b1_1 = *(const s16x8*)(pb1 + k3);
    }
    compute();
  }

  // C/D layout: row = q*4+j, col = r  [m89/m91]
#pragma unroll
  for (int nn = 0; nn < 4; nn++){
    size_t col = n0 + wn*64 + nn*16 + r;
    float bv = 0.0f;
    if (MODE != 0 && (SPLITK == 1 || blockIdx.z == 0)) bv = bias[col];
#pragma unroll
    for (int mm = 0; mm < 4; mm++){
#pragma unroll
      for (int j = 0; j < 4; j++){
        size_t row = m0 + wm*64 + mm*16 + q*4 + j;
        float v = acc[mm][nn][j] + bv;
        if (MODE == 1) v = 0.5f * v * (1.0f + erff(v * 0.70710678118654752f));
        if (MODE == 2){
          if (SPLITK > 1) atomicAdd(&resid[row * N + col], v);
          else            resid[row * N + col] += v;
        } else {
          outb[row * N + col] = f2b(v);
        }
      }
    }
  }
}

// ---------------------------------------------------------------------------
// Zero-sink attention (flash-style). grid=(Nq/64, H, B), block=256 (4 waves).
// V comes PRE-TRANSPOSED in global: vT[b][768][Nkv] (head h at rows h*64..).
// KVBLK=64: K tile [64][64] and Vt tile [64][64], BOTH with xor-chunk swizzle
// applied on the GLOBAL side (linear b128 LDS stores = conflict-free; swizzled
// b128 reads = 2-way max).
// SOFTMAX WITHOUT MAX-TRACKING (round-3): softmax is shift-invariant and the
// zero-sink pins the reference shift at 0; logits here are tiny (LN'd acts x
// 0.02-scale weights -> |s| < ~5, fp32 exp overflows only past 88), so
// p = exp(s) directly. Row-sum l via MFMA with a ones B-fragment.
// ---------------------------------------------------------------------------
__launch_bounds__(256, 4)
__global__ void attn_zero_kernel(const u16* __restrict__ Qp, const u16* __restrict__ Kp,
                                 const u16* __restrict__ vT, u16* __restrict__ Op,
                                 int Nq, int Nkv, int LDq, int LDk,
                                 float outw, int accumulate)
{
  __shared__ __align__(16) u16 lds_k[64*64];        // [kv][d], chunk-swizzled
  __shared__ __align__(16) u16 lds_v[64*64];        // [d][kv], chunk-swizzled
  __shared__ __align__(16) u16 lds_p[4][2][16*40];  // per-wave P halves, pitch 40

  const int tid = threadIdx.x;
  const int w = tid >> 6, l = tid & 63;
  const int q = l >> 4, r = l & 15;
  const int h = blockIdx.y, b = blockIdx.z;
  const int q0 = blockIdx.x * 64 + w * 16;

  s16x8 qf[2];
  {
    const u16* qrow = Qp + (size_t)(b*Nq + q0 + r) * LDq + h*64;
    qf[0] = *(const s16x8*)(qrow + q*8);
    qf[1] = *(const s16x8*)(qrow + 32 + q*8);
  }

  f32x4 o[4];
  f32x4 lsum;
  f32x4 zero = {0.f, 0.f, 0.f, 0.f};
#pragma unroll
  for (int nn = 0; nn < 4; nn++) o[nn] = zero;
  lsum = zero;
  const s16x8 ones = {(short)0x3F80, (short)0x3F80, (short)0x3F80, (short)0x3F80,
                      (short)0x3F80, (short)0x3F80, (short)0x3F80, (short)0x3F80}; // bf16 1.0
  const float C2 = 0.18033688011112042f;   // 0.125 * log2(e): exp(s*0.125) = exp2(s*C2)

  // staging: chunk c -> row=c>>3, slot-chunk cc=c&7, global-chunk cc^(row&7).
  // thread stages chunks {tid, 256+tid} (rows 0..31, 32..63; (row+32)&7==row&7).
  const int crow = tid >> 3;
  const int ccol = ((tid & 7) ^ (crow & 7)) << 3;
  const u16* Kbase = Kp + (size_t)b * Nkv * LDk + h*64;
  const u16* gk = Kbase + (size_t)crow * LDk + ccol;
  const u16* Vbase = vT + ((size_t)b * 768 + h*64) * (size_t)Nkv;
  const u16* gv = Vbase + (size_t)crow * Nkv + ccol;
  const size_t gk32 = (size_t)32 * LDk;   // +32 kv rows (K)
  const size_t gv32 = (size_t)32 * Nkv;   // +32 d rows (Vt)

  // prefetch tile 0
  s16x8 kr0 = *(const s16x8*)(gk);
  s16x8 kr1 = *(const s16x8*)(gk + gk32);
  s16x8 vr0 = *(const s16x8*)(gv);
  s16x8 vr1 = *(const s16x8*)(gv + gv32);

  for (int kv0 = 0; kv0 < Nkv; kv0 += 64){
    __syncthreads();
    *(s16x8*)&lds_k[tid * 8]         = kr0;   // contiguous b128 stores
    *(s16x8*)&lds_k[(256 + tid) * 8] = kr1;
    *(s16x8*)&lds_v[tid * 8]         = vr0;
    *(s16x8*)&lds_v[(256 + tid) * 8] = vr1;
    __syncthreads();
    if (kv0 + 64 < Nkv){                  // issue next tile's loads (no wait)
      const u16* gkn = gk + (size_t)(kv0 + 64) * LDk;
      kr0 = *(const s16x8*)(gkn);
      kr1 = *(const s16x8*)(gkn + gk32);
      vr0 = *(const s16x8*)(gv + (kv0 + 64));
      vr1 = *(const s16x8*)(gv + (kv0 + 64) + gv32);
    }

    // S = Q K^T (raw logits; 0.125 scale folded into exp2 constant)
    f32x4 s[4];
#pragma unroll
    for (int kk = 0; kk < 4; kk++){
      int row = kk*16 + r;
      s16x8 kf0 = *(const s16x8*)&lds_k[row*64 + ((q       ^ (row & 7)) << 3)];
      s16x8 kf1 = *(const s16x8*)&lds_k[row*64 + (((4 + q) ^ (row & 7)) << 3)];
      f32x4 t = zero;
      t = __builtin_amdgcn_mfma_f32_16x16x32_bf16(qf[0], kf0, t, 0, 0, 0);
      t = __builtin_amdgcn_mfma_f32_16x16x32_bf16(qf[1], kf1, t, 0, 0, 0);
      s[kk] = t;
    }

    // P = exp(s/8), straight to bf16 (no max-tracking, no rescale)
    u16* P0 = &lds_p[w][0][0];
    u16* P1 = &lds_p[w][1][0];
#pragma unroll
    for (int j = 0; j < 4; j++){
      P0[(q*4 + j)*40 + r]      = f2b(exp2f(s[0][j] * C2));
      P0[(q*4 + j)*40 + 16 + r] = f2b(exp2f(s[1][j] * C2));
      P1[(q*4 + j)*40 + r]      = f2b(exp2f(s[2][j] * C2));
      P1[(q*4 + j)*40 + 16 + r] = f2b(exp2f(s[3][j] * C2));
    }
    s16x8 pf0 = *(const s16x8*)&P0[r*40 + q*8];
    s16x8 pf1 = *(const s16x8*)&P1[r*40 + q*8];
#pragma unroll
    for (int nn = 0; nn < 4; nn++){
      int row = nn*16 + r;                   // d index (B-fragment n)
      s16x8 vf0 = *(const s16x8*)&lds_v[row*64 + ((q       ^ (row & 7)) << 3)];
      s16x8 vf1 = *(const s16x8*)&lds_v[row*64 + (((4 + q) ^ (row & 7)) << 3)];
      o[nn] = __builtin_amdgcn_mfma_f32_16x16x32_bf16(pf0, vf0, o[nn], 0, 0, 0);
      o[nn] = __builtin_amdgcn_mfma_f32_16x16x32_bf16(pf1, vf1, o[nn], 0, 0, 0);
    }
    // row-sum of P via ones-B MFMA (C layout row=q*4+j, col=r; cols identical)
    lsum = __builtin_amdgcn_mfma_f32_16x16x32_bf16(pf0, ones, lsum, 0, 0, 0);
    lsum = __builtin_amdgcn_mfma_f32_16x16x32_bf16(pf1, ones, lsum, 0, 0, 0);
  }

#pragma unroll
  for (int j = 0; j < 4; j++){
    float inv = outw / (1.0f + lsum[j]);     // sink contributes exp(0)=1
    size_t rowoff = (size_t)(b*Nq + q0 + q*4 + j) * 768 + h*64;
#pragma unroll
    for (int nn = 0; nn < 4; nn++){
      float v = o[nn][j] * inv;
      size_t idx = rowoff + nn*16 + r;
      if (accumulate) v += b2f(Op[idx]);
      Op[idx] = f2b(v);
    }
  }
}

// ---------------------------------------------------------------------------
// LayerNorm over D=768 fp32 rows -> bf16 out. One block (256) per row.
// ---------------------------------------------------------------------------
__launch_bounds__(256)
__global__ void ln_kernel(const float* __restrict__ x, const float* __restrict__ g,
                          const float* __restrict__ bta, u16* __restrict__ out)
{
  __shared__ float red[8];
  const size_t row = blockIdx.x;
  const float* xr = x + row * 768;
  int t = threadIdx.x;
  float v0 = xr[t], v1 = xr[t + 256], v2 = xr[t + 512];
  float s  = v0 + v1 + v2;
  float s2 = v0*v0 + v1*v1 + v2*v2;
#pragma unroll
  for (int d = 1; d < 64; d <<= 1){ s += __shfl_xor(s, d); s2 += __shfl_xor(s2, d); }
  int w = t >> 6;
  if ((t & 63) == 0){ red[w] = s; red[4 + w] = s2; }
  __syncthreads();
  s  = red[0] + red[1] + red[2] + red[3];
  s2 = red[4] + red[5] + red[6] + red[7];
  float mean = s * (1.0f / 768.0f);
  float var  = s2 * (1.0f / 768.0f) - mean * mean;
  float rstd = rsqrtf(var + 1e-5f);
  u16* orow = out + row * 768;
  orow[t]       = f2b((v0 - mean) * rstd * g[t]       + bta[t]);
  orow[t + 256] = f2b((v1 - mean) * rstd * g[t + 256] + bta[t + 256]);
  orow[t + 512] = f2b((v2 - mean) * rstd * g[t + 512] + bta[t + 512]);
}

// fp32 -> bf16 transpose (R x C -> C x R), dims multiples of 64. block (64,4).
__global__ void transpose_kernel(const float* __restrict__ in, u16* __restrict__ out, int R, int C)
{
  __shared__ u16 tile[64][65];
  int c0 = blockIdx.x * 64, r0 = blockIdx.y * 64;
  for (int i = threadIdx.y; i < 64; i += 4)
    tile[i][threadIdx.x] = f2b(in[(size_t)(r0 + i) * C + c0 + threadIdx.x]);
  __syncthreads();
  for (int i = threadIdx.y; i < 64; i += 4)
    out[(size_t)(c0 + i) * R + r0 + threadIdx.x] = tile[threadIdx.x][i];
}

// batched u16 transpose for V: in = per-batch [N][LD] slab at col offset coff,
// out = [b][768][N]. grid (768/64, N/64, B), block (64,4).
__global__ void transpose_v_kernel(const u16* __restrict__ in, u16* __restrict__ out,
                                   int N, int LD, int coff)
{
  __shared__ u16 tile[64][65];
  int bz = blockIdx.z;
  int c0 = blockIdx.x * 64, n0 = blockIdx.y * 64;
  const u16* ib = in + ((size_t)bz * N + n0) * LD + coff + c0;
  for (int i = threadIdx.y; i < 64; i += 4)
    tile[i][threadIdx.x] = ib[(size_t)i * LD + threadIdx.x];     // token n0+i, chan c0+tx
  __syncthreads();
  u16* ob = out + ((size_t)bz * 768 + c0) * N + n0;
  for (int i = threadIdx.y; i < 64; i += 4)
    ob[(size_t)i * N + threadIdx.x] = tile[threadIdx.x][i];      // chan c0+i, token n0+tx
}

// fp32 vectorized copy (n multiple of 4).
__global__ void copy_f32(const float* __restrict__ in, float* __restrict__ out, long n4){
  long i = (long)blockIdx.x * blockDim.x + threadIdx.x;
  long stride = (long)gridDim.x * blockDim.x;
  const f32x4* in4 = (const f32x4*)in;
  f32x4* out4 = (f32x4*)out;
  for (; i < n4; i += stride) out4[i] = in4[i];
}

// ---------------------------------------------------------------------------
extern "C" void kernel_launch(void* const* d_in, const int* in_sizes, int n_in,
                              void* d_out, int out_size, void* d_ws, size_t ws_size,
                              hipStream_t stream)
{
  const int B = 4, NI = 1024, NC = 256, D = 768, FF = 3072, H = 12, L = 2;
  const int RI = B * NI;   // 4096 img rows
  const int RC = B * NC;   // 1024 clinic rows

  const float* img    = (const float*)d_in[0];
  const float* clinic = (const float*)d_in[1];
  const float* ln1_g  = (const float*)d_in[2];
  const float* ln1_b  = (const float*)d_in[3];
  const float* w_qkv  = (const float*)d_in[4];
  const float* w_o    = (const float*)d_in[5];
  const float* b_o    = (const float*)d_in[6];
  const float* ln2_g  = (const float*)d_in[7];
  const float* ln2_b  = (const float*)d_in[8];
  const float* w_ff1  = (const float*)d_in[9];
  const float* b_ff1  = (const float*)d_in[10];
  const float* w_ff2  = (const float*)d_in[11];
  const float* b_ff2  = (const float*)d_in[12];
  const float* cn_i_g = (const float*)d_in[13];
  const float* cn_i_b = (const float*)d_in[14];
  const float* cn_c_g = (const float*)d_in[15];
  const float* cn_c_b = (const float*)d_in[16];
  const float* w_iq   = (const float*)d_in[17];
  const float* w_ik   = (const float*)d_in[18];
  const float* w_iv   = (const float*)d_in[19];
  const float* w_cq   = (const float*)d_in[20];
  const float* w_ck   = (const float*)d_in[21];
  const float* w_cv   = (const float*)d_in[22];
  const float* w_io   = (const float*)d_in[23];
  const float* b_io   = (const float*)d_in[24];
  const float* w_co   = (const float*)d_in[25];
  const float* b_co   = (const float*)d_in[26];
  const float* fn_i_g = (const float*)d_in[27];
  const float* fn_i_b = (const float*)d_in[28];
  const float* fn_c_g = (const float*)d_in[29];
  const float* fn_c_b = (const float*)d_in[30];
  const float* iff_w1 = (const float*)d_in[31];
  const float* iff_b1 = (const float*)d_in[32];
  const float* iff_w2 = (const float*)d_in[33];
  const float* iff_b2 = (const float*)d_in[34];
  const float* cff_w1 = (const float*)d_in[35];
  const float* cff_b1 = (const float*)d_in[36];
  const float* cff_w2 = (const float*)d_in[37];
  const float* cff_b2 = (const float*)d_in[38];

  // ---- workspace carve (~121 MB) ----
  char* ws = (char*)d_ws;
  size_t off = 0;
  auto alloc = [&](size_t elems, size_t esz) -> void* {
    void* p = ws + off;
    off += ((elems * esz) + 255) & ~(size_t)255;
    return p;
  };
  u16* wqkvT[2]; u16* woT[2]; u16* ff1T[2]; u16* ff2T[2];
  for (int i = 0; i < 2; i++) wqkvT[i] = (u16*)alloc((size_t)3*D*D, 2);
  for (int i = 0; i < 2; i++) woT[i]   = (u16*)alloc((size_t)D*D, 2);
  for (int i = 0; i < 2; i++) ff1T[i]  = (u16*)alloc((size_t)FF*D, 2);
  for (int i = 0; i < 2; i++) ff2T[i]  = (u16*)alloc((size_t)D*FF, 2);
  u16* wiqkvT = (u16*)alloc((size_t)3*D*D, 2);   // fused [iq|ik|iv] as [2304][768]
  u16* wcqkvT = (u16*)alloc((size_t)3*D*D, 2);   // fused [cq|ck|cv]
  u16* wioT = (u16*)alloc((size_t)D*D, 2); u16* wcoT = (u16*)alloc((size_t)D*D, 2);
  u16* iff1T = (u16*)alloc((size_t)FF*D, 2); u16* iff2T = (u16*)alloc((size_t)D*FF, 2);
  u16* cff1T = (u16*)alloc((size_t)FF*D, 2); u16* cff2T = (u16*)alloc((size_t)D*FF, 2);

  float* img_f = (float*)alloc((size_t)RI*D, 4);   // fp32 residual streams
  float* cli_f = (float*)alloc((size_t)RC*D, 4);
  u16* xn_i = (u16*)alloc((size_t)RI*D, 2);
  u16* xn_c = (u16*)alloc((size_t)RC*D, 2);
  // shared region: {qkvb | cqkv} (projections) or {h1} (FFN hidden)
  u16* region = (u16*)alloc((size_t)RI*FF, 2);   // RI*FF > RI*3D + RC*3D
  u16* qkvb = region;
  u16* cqkv = region + (size_t)RI*3*D;
  u16* h1   = region;
  u16* ao_i = (u16*)alloc((size_t)RI*D, 2);      // attention outputs (bf16)
  u16* ao_c = (u16*)alloc((size_t)RC*D, 2);
  u16* vT_i = (u16*)alloc((size_t)B*D*NI, 2);    // pre-transposed V, img stream
  u16* vT_c = (u16*)alloc((size_t)B*D*NC, 2);    // pre-transposed V, clinic stream
  (void)ws_size; (void)in_sizes; (void)n_in; (void)out_size;

  auto T = [&](const float* in_, u16* out_, int R, int C){
    transpose_kernel<<<dim3(C/64, R/64), dim3(64, 4), 0, stream>>>(in_, out_, R, C);
  };
  auto TV = [&](const u16* in_, u16* out_, int N, int LD, int coff){
    transpose_v_kernel<<<dim3(D/64, N/64, B), dim3(64, 4), 0, stream>>>(in_, out_, N, LD, coff);
  };
  auto G0 = [&](const u16* A, const u16* Bt, u16* out_, int M, int N, int K){
    gemm_bt<0,1><<<dim3(N/128, M/128), 256, 0, stream>>>(A, Bt, nullptr, out_, nullptr, M, N, K);
  };
  auto G1 = [&](const u16* A, const u16* Bt, const float* bias, u16* out_, int M, int N, int K){
    gemm_bt<1,1><<<dim3(N/128, M/128), 256, 0, stream>>>(A, Bt, bias, out_, nullptr, M, N, K);
  };
  auto G2 = [&](const u16* A, const u16* Bt, const float* bias, float* resid, int M, int N, int K, int splitk){
    if (splitk == 4)
      gemm_bt<2,4><<<dim3(N/128, M/128, 4), 256, 0, stream>>>(A, Bt, bias, nullptr, resid, M, N, K);
    else if (splitk == 2)
      gemm_bt<2,2><<<dim3(N/128, M/128, 2), 256, 0, stream>>>(A, Bt, bias, nullptr, resid, M, N, K);
    else
      gemm_bt<2,1><<<dim3(N/128, M/128, 1), 256, 0, stream>>>(A, Bt, bias, nullptr, resid, M, N, K);
  };
  auto ATT = [&](const u16* Q, const u16* K_, const u16* vTp, u16* O,
                 int Nq, int Nkv, int LDq, int LDk, float w_, int acc_){
    attn_zero_kernel<<<dim3(Nq/64, H, B), 256, 0, stream>>>(Q, K_, vTp, O, Nq, Nkv, LDq, LDk, w_, acc_);
  };
  auto CP = [&](const float* in_, float* out_, long n){
    copy_f32<<<1024, 256, 0, stream>>>(in_, out_, n / 4);
  };

  // ---- weight pre-transposes (K x N fp32 -> N x K bf16) ----
  for (int li = 0; li < L; li++){
    T(w_qkv + (size_t)li*D*3*D, wqkvT[li], D, 3*D);
    T(w_o   + (size_t)li*D*D,   woT[li],   D, D);
    T(w_ff1 + (size_t)li*D*FF,  ff1T[li],  D, FF);
    T(w_ff2 + (size_t)li*FF*D,  ff2T[li],  FF, D);
  }
  T(w_iq, wiqkvT,              D, D);
  T(w_ik, wiqkvT + (size_t)D*D,   D, D);
  T(w_iv, wiqkvT + (size_t)2*D*D, D, D);
  T(w_cq, wcqkvT,              D, D);
  T(w_ck, wcqkvT + (size_t)D*D,   D, D);
  T(w_cv, wcqkvT + (size_t)2*D*D, D, D);
  T(w_io, wioT, D, D); T(w_co, wcoT, D, D);
  T(iff_w1, iff1T, D, FF); T(iff_w2, iff2T, FF, D);
  T(cff_w1, cff1T, D, FF); T(cff_w2, cff2T, FF, D);

  // ---- fp32 residual streams ----
  CP(img,    img_f, (long)RI*D);
  CP(clinic, cli_f, (long)RC*D);

  // ---- transformer stack ----
  for (int li = 0; li < L; li++){
    ln_kernel<<<RI, 256, 0, stream>>>(img_f, ln1_g + li*D, ln1_b + li*D, xn_i);
    G0(xn_i, wqkvT[li], qkvb, RI, 3*D, D);
    TV(qkvb, vT_i, NI, 3*D, 2*D);                      // V slice -> [b][768][NI]
    ATT(qkvb, qkvb + D, vT_i, ao_i, NI, NI, 3*D, 3*D, 1.0f, 0);
    G2(ao_i, woT[li], b_o + li*D, img_f, RI, D, D, 2);
    ln_kernel<<<RI, 256, 0, stream>>>(img_f, ln2_g + li*D, ln2_b + li*D, xn_i);
    G1(xn_i, ff1T[li], b_ff1 + li*FF, h1, RI, FF, D);
    G2(h1, ff2T[li], b_ff2 + li*D, img_f, RI, D, FF, 2);
  }

  // ---- cross block ----
  ln_kernel<<<RI, 256, 0, stream>>>(img_f, cn_i_g, cn_i_b, xn_i);
  ln_kernel<<<RC, 256, 0, stream>>>(cli_f, cn_c_g, cn_c_b, xn_c);
  u16* iqkv = qkvb;   // [RI][3D]: iq | ik | iv
  u16* cqk  = cqkv;   // [RC][3D]: cq | ck | cv
  G0(xn_i, wiqkvT, iqkv, RI, 3*D, D);
  G0(xn_c, wcqkvT, cqk,  RC, 3*D, D);
  TV(iqkv, vT_i, NI, 3*D, 2*D);
  TV(cqk,  vT_c, NC, 3*D, 2*D);

  ATT(iqkv, cqk + D,  vT_c, ao_i, NI, NC, 3*D, 3*D, 0.5f, 0);
  ATT(iqkv, iqkv + D, vT_i, ao_i, NI, NI, 3*D, 3*D, 0.5f, 1);
  ATT(cqk,  iqkv + D, vT_i, ao_c, NC, NI, 3*D, 3*D, 0.5f, 0);
  ATT(cqk,  cqk + D,  vT_c, ao_c, NC, NC, 3*D, 3*D, 0.5f, 1);

  G2(ao_i, wioT, b_io, img_f, RI, D, D, 2);
  G2(ao_c, wcoT, b_co, cli_f, RC, D, D, 4);

  ln_kernel<<<RI, 256, 0, stream>>>(img_f, fn_i_g, fn_i_b, xn_i);
  G1(xn_i, iff1T, iff_b1, h1, RI, FF, D);
  G2(h1, iff2T, iff_b2, img_f, RI, D, FF, 2);

  ln_kernel<<<RC, 256, 0, stream>>>(cli_f, fn_c_g, fn_c_b, xn_c);
  G1(xn_c, cff1T, cff_b1, h1, RC, FF, D);
  G2(h1, cff2T, cff_b2, cli_f, RC, D, FF, 4);

  // ---- emit fp32 outputs (img then clinic, flat) ----
  CP(img_f, (float*)d_out,                (long)RI*D);
  CP(cli_f, (float*)d_out + (size_t)RI*D, (long)RC*D);
}

// Round 9
// 943.173 us; speedup vs baseline: 1.0414x; 1.0096x over previous
//
#include <hip/hip_runtime.h>
#include <stdint.h>
#include <math.h>

typedef unsigned short u16;
typedef short  s16x8 __attribute__((ext_vector_type(8)));
typedef float  f32x4 __attribute__((ext_vector_type(4)));

#define DEVI __device__ __forceinline__

DEVI float b2f(u16 u){ union{unsigned int i; float f;} v; v.i = ((unsigned int)u)<<16; return v.f; }
DEVI u16 f2b(float f){
  union{float f; unsigned int i;} v; v.f = f;
  unsigned int r = v.i + 0x7FFFu + ((v.i >> 16) & 1u);   // RNE
  return (u16)(r >> 16);
}

// ---------------------------------------------------------------------------
// GEMM: C[M,N] = A[M,K] @ Bt[N,K]^T   (A,Bt bf16, fp32 accum, fp32 bias)
// MODE 0: store bf16 | MODE 1: bias + exact GELU, store bf16
// MODE 2: resid_f32[M,N] += acc + bias  (SPLITK>1: atomicAdd, bias on z==0)
// 128x128 tile, BK=32, 4 waves (2x2), 16x16x32 bf16 MFMA, 2-deep reg prefetch.
// r9: LDS DOUBLE-BUFFER, ONE barrier/iteration. Evidence trail: dur pinned at
// 46us across {TLP x2 (r6), 4-deep prefetch (r7), BM=64 (r6), FETCH 86->31MB
// (r8 XCD swizzle)} => not bytes/latency/occupancy-bound. Remaining invariant
// was 2 full-drain barriers per 32-K iteration (~2300cyc/iter vs ~160cyc
// MFMA). Single-barrier dbuf is WAR-safe: reaching store(buf p) at iter i+2
// requires passing barrier i+1, which requires all waves past compute(buf p)
// at iter i. Stores now overlap other waves' compute of the other buffer.
// Keep: 2-deep reg prefetch (r1: gload_lds+drain regressed), splitk<=2 RI
// (r4: atomic RMW), XCD swizzle (r8: FETCH 2.7x better, latency-neutral).
// niter must be EVEN (all call shapes satisfy).
// ---------------------------------------------------------------------------
template<int MODE, int SPLITK>
__launch_bounds__(256, 2)
__global__ void gemm_bt(const u16* __restrict__ A, const u16* __restrict__ Bt,
                        const float* __restrict__ bias, u16* __restrict__ outb,
                        float* __restrict__ resid, int M, int N, int K)
{
  __shared__ __align__(16) u16 lds_a[2][128*32];
  __shared__ __align__(16) u16 lds_b[2][128*32];
  const int tid = threadIdx.x;
  const int w = tid >> 6, l = tid & 63;
  const int q = l >> 4, r = l & 15;
  const int wm = w & 1, wn = w >> 1;

  // XCD-aware tile remap: hw XCD ~ linear_bid % 8; give XCD k the contiguous
  // tile range [k*q8,(k+1)*q8) in row-major (x fastest) order.
  int bx = blockIdx.x, by = blockIdx.y;
  {
    const int nwg = gridDim.x * gridDim.y;      // per z-slice; %8==0 for all calls
    const int bid = by * gridDim.x + bx;
    const int q8 = nwg >> 3;
    const int t = (bid & 7) * q8 + (bid >> 3);
    bx = t % gridDim.x;
    by = t / gridDim.x;
  }
  const size_t m0 = (size_t)by * 128, n0 = (size_t)bx * 128;
  const int kslice = K / SPLITK;
  const int kbeg = (SPLITK > 1) ? (int)blockIdx.z * kslice : 0;

  const int srow = tid >> 2;            // staging row 0..63
  const int scol = (tid & 3) * 8;       // staging col (u16) 0/8/16/24
  const u16* pa0 = A  + (m0 + srow)      * (size_t)K + kbeg + scol;
  const u16* pa1 = A  + (m0 + 64 + srow) * (size_t)K + kbeg + scol;
  const u16* pb0 = Bt + (n0 + srow)      * (size_t)K + kbeg + scol;
  const u16* pb1 = Bt + (n0 + 64 + srow) * (size_t)K + kbeg + scol;

  f32x4 acc[4][4];
  f32x4 zero = {0.f, 0.f, 0.f, 0.f};
#pragma unroll
  for (int i = 0; i < 4; i++)
#pragma unroll
    for (int j = 0; j < 4; j++) acc[i][j] = zero;

  auto compute = [&](const u16* La, const u16* Lb) {
    s16x8 af[4], bfr[4];
#pragma unroll
    for (int mm = 0; mm < 4; mm++)
      af[mm] = *(const s16x8*)&La[(wm*64 + mm*16 + r)*32 + q*8];
#pragma unroll
    for (int nn = 0; nn < 4; nn++)
      bfr[nn] = *(const s16x8*)&Lb[(wn*64 + nn*16 + r)*32 + q*8];
#pragma unroll
    for (int mm = 0; mm < 4; mm++)
#pragma unroll
      for (int nn = 0; nn < 4; nn++)
        acc[mm][nn] = __builtin_amdgcn_mfma_f32_16x16x32_bf16(af[mm], bfr[nn], acc[mm][nn], 0, 0, 0);
  };

  // two register buffer sets (tiles t and t+1), 2-deep prefetch pipeline
  s16x8 a0_0 = *(const s16x8*)(pa0);
  s16x8 a1_0 = *(const s16x8*)(pa1);
  s16x8 b0_0 = *(const s16x8*)(pb0);
  s16x8 b1_0 = *(const s16x8*)(pb1);
  s16x8 a0_1 = *(const s16x8*)(pa0 + 32);
  s16x8 a1_1 = *(const s16x8*)(pa1 + 32);
  s16x8 b0_1 = *(const s16x8*)(pb0 + 32);
  s16x8 b1_1 = *(const s16x8*)(pb1 + 32);

  const int niter = kslice / 32;         // even by construction
  for (int it = 0; it < niter; it += 2){
    // ---- even tile -> LDS buffer 0 ----
    *(s16x8*)&lds_a[0][srow*32 + scol]        = a0_0;
    *(s16x8*)&lds_a[0][(64 + srow)*32 + scol] = a1_0;
    *(s16x8*)&lds_b[0][srow*32 + scol]        = b0_0;
    *(s16x8*)&lds_b[0][(64 + srow)*32 + scol] = b1_0;
    __syncthreads();                      // stores visible; prior buf0 reads done
    if (it + 2 < niter){                  // issue loads for tile it+2 (no wait)
      int k2 = (it + 2) * 32;
      a0_0 = *(const s16x8*)(pa0 + k2);
      a1_0 = *(const s16x8*)(pa1 + k2);
      b0_0 = *(const s16x8*)(pb0 + k2);
      b1_0 = *(const s16x8*)(pb1 + k2);
    }
    compute(lds_a[0], lds_b[0]);
    // ---- odd tile -> LDS buffer 1 (no barrier before store: other buffer) ----
    *(s16x8*)&lds_a[1][srow*32 + scol]        = a0_1;
    *(s16x8*)&lds_a[1][(64 + srow)*32 + scol] = a1_1;
    *(s16x8*)&lds_b[1][srow*32 + scol]        = b0_1;
    *(s16x8*)&lds_b[1][(64 + srow)*32 + scol] = b1_1;
    __syncthreads();
    if (it + 3 < niter){                  // issue loads for tile it+3
      int k3 = (it + 3) * 32;
      a0_1 = *(const s16x8*)(pa0 + k3);
      a1_1 = *(const s16x8*)(pa1 + k3);
      b0_1 = *(const s16x8*)(pb0 + k3);
      b1_1 = *(const s16x8*)(pb1 + k3);
    }
    compute(lds_a[1], lds_b[1]);
  }

  // C/D layout: row = q*4+j, col = r  [m89/m91]
#pragma unroll
  for (int nn = 0; nn < 4; nn++){
    size_t col = n0 + wn*64 + nn*16 + r;
    float bv = 0.0f;
    if (MODE != 0 && (SPLITK == 1 || blockIdx.z == 0)) bv = bias[col];
#pragma unroll
    for (int mm = 0; mm < 4; mm++){
#pragma unroll
      for (int j = 0; j < 4; j++){
        size_t row = m0 + wm*64 + mm*16 + q*4 + j;
        float v = acc[mm][nn][j] + bv;
        if (MODE == 1) v = 0.5f * v * (1.0f + erff(v * 0.70710678118654752f));
        if (MODE == 2){
          if (SPLITK > 1) atomicAdd(&resid[row * N + col], v);
          else            resid[row * N + col] += v;
        } else {
          outb[row * N + col] = f2b(v);
        }
      }
    }
  }
}

// ---------------------------------------------------------------------------
// Zero-sink attention (flash-style). grid=(Nq/64, H, B), block=256 (4 waves).
// V comes PRE-TRANSPOSED in global: vT[b][768][Nkv] (head h at rows h*64..).
// KVBLK=64: K tile [64][64] and Vt tile [64][64], BOTH with xor-chunk swizzle
// applied on the GLOBAL side (linear b128 LDS stores = conflict-free; swizzled
// b128 reads = 2-way max).
// SOFTMAX WITHOUT MAX-TRACKING (round-3): softmax is shift-invariant and the
// zero-sink pins the reference shift at 0; logits here are tiny (LN'd acts x
// 0.02-scale weights -> |s| < ~5, fp32 exp overflows only past 88), so
// p = exp(s) directly. Row-sum l via MFMA with a ones B-fragment.
// ---------------------------------------------------------------------------
__launch_bounds__(256, 4)
__global__ void attn_zero_kernel(const u16* __restrict__ Qp, const u16* __restrict__ Kp,
                                 const u16* __restrict__ vT, u16* __restrict__ Op,
                                 int Nq, int Nkv, int LDq, int LDk,
                                 float outw, int accumulate)
{
  __shared__ __align__(16) u16 lds_k[64*64];        // [kv][d], chunk-swizzled
  __shared__ __align__(16) u16 lds_v[64*64];        // [d][kv], chunk-swizzled
  __shared__ __align__(16) u16 lds_p[4][2][16*40];  // per-wave P halves, pitch 40

  const int tid = threadIdx.x;
  const int w = tid >> 6, l = tid & 63;
  const int q = l >> 4, r = l & 15;
  const int h = blockIdx.y, b = blockIdx.z;
  const int q0 = blockIdx.x * 64 + w * 16;

  s16x8 qf[2];
  {
    const u16* qrow = Qp + (size_t)(b*Nq + q0 + r) * LDq + h*64;
    qf[0] = *(const s16x8*)(qrow + q*8);
    qf[1] = *(const s16x8*)(qrow + 32 + q*8);
  }

  f32x4 o[4];
  f32x4 lsum;
  f32x4 zero = {0.f, 0.f, 0.f, 0.f};
#pragma unroll
  for (int nn = 0; nn < 4; nn++) o[nn] = zero;
  lsum = zero;
  const s16x8 ones = {(short)0x3F80, (short)0x3F80, (short)0x3F80, (short)0x3F80,
                      (short)0x3F80, (short)0x3F80, (short)0x3F80, (short)0x3F80}; // bf16 1.0
  const float C2 = 0.18033688011112042f;   // 0.125 * log2(e): exp(s*0.125) = exp2(s*C2)

  // staging: chunk c -> row=c>>3, slot-chunk cc=c&7, global-chunk cc^(row&7).
  // thread stages chunks {tid, 256+tid} (rows 0..31, 32..63; (row+32)&7==row&7).
  const int crow = tid >> 3;
  const int ccol = ((tid & 7) ^ (crow & 7)) << 3;
  const u16* Kbase = Kp + (size_t)b * Nkv * LDk + h*64;
  const u16* gk = Kbase + (size_t)crow * LDk + ccol;
  const u16* Vbase = vT + ((size_t)b * 768 + h*64) * (size_t)Nkv;
  const u16* gv = Vbase + (size_t)crow * Nkv + ccol;
  const size_t gk32 = (size_t)32 * LDk;   // +32 kv rows (K)
  const size_t gv32 = (size_t)32 * Nkv;   // +32 d rows (Vt)

  // prefetch tile 0
  s16x8 kr0 = *(const s16x8*)(gk);
  s16x8 kr1 = *(const s16x8*)(gk + gk32);
  s16x8 vr0 = *(const s16x8*)(gv);
  s16x8 vr1 = *(const s16x8*)(gv + gv32);

  for (int kv0 = 0; kv0 < Nkv; kv0 += 64){
    __syncthreads();
    *(s16x8*)&lds_k[tid * 8]         = kr0;   // contiguous b128 stores
    *(s16x8*)&lds_k[(256 + tid) * 8] = kr1;
    *(s16x8*)&lds_v[tid * 8]         = vr0;
    *(s16x8*)&lds_v[(256 + tid) * 8] = vr1;
    __syncthreads();
    if (kv0 + 64 < Nkv){                  // issue next tile's loads (no wait)
      const u16* gkn = gk + (size_t)(kv0 + 64) * LDk;
      kr0 = *(const s16x8*)(gkn);
      kr1 = *(const s16x8*)(gkn + gk32);
      vr0 = *(const s16x8*)(gv + (kv0 + 64));
      vr1 = *(const s16x8*)(gv + (kv0 + 64) + gv32);
    }

    // S = Q K^T (raw logits; 0.125 scale folded into exp2 constant)
    f32x4 s[4];
#pragma unroll
    for (int kk = 0; kk < 4; kk++){
      int row = kk*16 + r;
      s16x8 kf0 = *(const s16x8*)&lds_k[row*64 + ((q       ^ (row & 7)) << 3)];
      s16x8 kf1 = *(const s16x8*)&lds_k[row*64 + (((4 + q) ^ (row & 7)) << 3)];
      f32x4 t = zero;
      t = __builtin_amdgcn_mfma_f32_16x16x32_bf16(qf[0], kf0, t, 0, 0, 0);
      t = __builtin_amdgcn_mfma_f32_16x16x32_bf16(qf[1], kf1, t, 0, 0, 0);
      s[kk] = t;
    }

    // P = exp(s/8), straight to bf16 (no max-tracking, no rescale)
    u16* P0 = &lds_p[w][0][0];
    u16* P1 = &lds_p[w][1][0];
#pragma unroll
    for (int j = 0; j < 4; j++){
      P0[(q*4 + j)*40 + r]      = f2b(exp2f(s[0][j] * C2));
      P0[(q*4 + j)*40 + 16 + r] = f2b(exp2f(s[1][j] * C2));
      P1[(q*4 + j)*40 + r]      = f2b(exp2f(s[2][j] * C2));
      P1[(q*4 + j)*40 + 16 + r] = f2b(exp2f(s[3][j] * C2));
    }
    s16x8 pf0 = *(const s16x8*)&P0[r*40 + q*8];
    s16x8 pf1 = *(const s16x8*)&P1[r*40 + q*8];
#pragma unroll
    for (int nn = 0; nn < 4; nn++){
      int row = nn*16 + r;                   // d index (B-fragment n)
      s16x8 vf0 = *(const s16x8*)&lds_v[row*64 + ((q       ^ (row & 7)) << 3)];
      s16x8 vf1 = *(const s16x8*)&lds_v[row*64 + (((4 + q) ^ (row & 7)) << 3)];
      o[nn] = __builtin_amdgcn_mfma_f32_16x16x32_bf16(pf0, vf0, o[nn], 0, 0, 0);
      o[nn] = __builtin_amdgcn_mfma_f32_16x16x32_bf16(pf1, vf1, o[nn], 0, 0, 0);
    }
    // row-sum of P via ones-B MFMA (C layout row=q*4+j, col=r; cols identical)
    lsum = __builtin_amdgcn_mfma_f32_16x16x32_bf16(pf0, ones, lsum, 0, 0, 0);
    lsum = __builtin_amdgcn_mfma_f32_16x16x32_bf16(pf1, ones, lsum, 0, 0, 0);
  }

#pragma unroll
  for (int j = 0; j < 4; j++){
    float inv = outw / (1.0f + lsum[j]);     // sink contributes exp(0)=1
    size_t rowoff = (size_t)(b*Nq + q0 + q*4 + j) * 768 + h*64;
#pragma unroll
    for (int nn = 0; nn < 4; nn++){
      float v = o[nn][j] * inv;
      size_t idx = rowoff + nn*16 + r;
      if (accumulate) v += b2f(Op[idx]);
      Op[idx] = f2b(v);
    }
  }
}

// ---------------------------------------------------------------------------
// LayerNorm over D=768 fp32 rows -> bf16 out. One block (256) per row.
// ---------------------------------------------------------------------------
__launch_bounds__(256)
__global__ void ln_kernel(const float* __restrict__ x, const float* __restrict__ g,
                          const float* __restrict__ bta, u16* __restrict__ out)
{
  __shared__ float red[8];
  const size_t row = blockIdx.x;
  const float* xr = x + row * 768;
  int t = threadIdx.x;
  float v0 = xr[t], v1 = xr[t + 256], v2 = xr[t + 512];
  float s  = v0 + v1 + v2;
  float s2 = v0*v0 + v1*v1 + v2*v2;
#pragma unroll
  for (int d = 1; d < 64; d <<= 1){ s += __shfl_xor(s, d); s2 += __shfl_xor(s2, d); }
  int w = t >> 6;
  if ((t & 63) == 0){ red[w] = s; red[4 + w] = s2; }
  __syncthreads();
  s  = red[0] + red[1] + red[2] + red[3];
  s2 = red[4] + red[5] + red[6] + red[7];
  float mean = s * (1.0f / 768.0f);
  float var  = s2 * (1.0f / 768.0f) - mean * mean;
  float rstd = rsqrtf(var + 1e-5f);
  u16* orow = out + row * 768;
  orow[t]       = f2b((v0 - mean) * rstd * g[t]       + bta[t]);
  orow[t + 256] = f2b((v1 - mean) * rstd * g[t + 256] + bta[t + 256]);
  orow[t + 512] = f2b((v2 - mean) * rstd * g[t + 512] + bta[t + 512]);
}

// fp32 -> bf16 transpose (R x C -> C x R), dims multiples of 64. block (64,4).
__global__ void transpose_kernel(const float* __restrict__ in, u16* __restrict__ out, int R, int C)
{
  __shared__ u16 tile[64][65];
  int c0 = blockIdx.x * 64, r0 = blockIdx.y * 64;
  for (int i = threadIdx.y; i < 64; i += 4)
    tile[i][threadIdx.x] = f2b(in[(size_t)(r0 + i) * C + c0 + threadIdx.x]);
  __syncthreads();
  for (int i = threadIdx.y; i < 64; i += 4)
    out[(size_t)(c0 + i) * R + r0 + threadIdx.x] = tile[threadIdx.x][i];
}

// batched u16 transpose for V: in = per-batch [N][LD] slab at col offset coff,
// out = [b][768][N]. grid (768/64, N/64, B), block (64,4).
__global__ void transpose_v_kernel(const u16* __restrict__ in, u16* __restrict__ out,
                                   int N, int LD, int coff)
{
  __shared__ u16 tile[64][65];
  int bz = blockIdx.z;
  int c0 = blockIdx.x * 64, n0 = blockIdx.y * 64;
  const u16* ib = in + ((size_t)bz * N + n0) * LD + coff + c0;
  for (int i = threadIdx.y; i < 64; i += 4)
    tile[i][threadIdx.x] = ib[(size_t)i * LD + threadIdx.x];     // token n0+i, chan c0+tx
  __syncthreads();
  u16* ob = out + ((size_t)bz * 768 + c0) * N + n0;
  for (int i = threadIdx.y; i < 64; i += 4)
    ob[(size_t)i * N + threadIdx.x] = tile[threadIdx.x][i];      // chan c0+i, token n0+tx
}

// fp32 vectorized copy (n multiple of 4).
__global__ void copy_f32(const float* __restrict__ in, float* __restrict__ out, long n4){
  long i = (long)blockIdx.x * blockDim.x + threadIdx.x;
  long stride = (long)gridDim.x * blockDim.x;
  const f32x4* in4 = (const f32x4*)in;
  f32x4* out4 = (f32x4*)out;
  for (; i < n4; i += stride) out4[i] = in4[i];
}

// ---------------------------------------------------------------------------
extern "C" void kernel_launch(void* const* d_in, const int* in_sizes, int n_in,
                              void* d_out, int out_size, void* d_ws, size_t ws_size,
                              hipStream_t stream)
{
  const int B = 4, NI = 1024, NC = 256, D = 768, FF = 3072, H = 12, L = 2;
  const int RI = B * NI;   // 4096 img rows
  const int RC = B * NC;   // 1024 clinic rows

  const float* img    = (const float*)d_in[0];
  const float* clinic = (const float*)d_in[1];
  const float* ln1_g  = (const float*)d_in[2];
  const float* ln1_b  = (const float*)d_in[3];
  const float* w_qkv  = (const float*)d_in[4];
  const float* w_o    = (const float*)d_in[5];
  const float* b_o    = (const float*)d_in[6];
  const float* ln2_g  = (const float*)d_in[7];
  const float* ln2_b  = (const float*)d_in[8];
  const float* w_ff1  = (const float*)d_in[9];
  const float* b_ff1  = (const float*)d_in[10];
  const float* w_ff2  = (const float*)d_in[11];
  const float* b_ff2  = (const float*)d_in[12];
  const float* cn_i_g = (const float*)d_in[13];
  const float* cn_i_b = (const float*)d_in[14];
  const float* cn_c_g = (const float*)d_in[15];
  const float* cn_c_b = (const float*)d_in[16];
  const float* w_iq   = (const float*)d_in[17];
  const float* w_ik   = (const float*)d_in[18];
  const float* w_iv   = (const float*)d_in[19];
  const float* w_cq   = (const float*)d_in[20];
  const float* w_ck   = (const float*)d_in[21];
  const float* w_cv   = (const float*)d_in[22];
  const float* w_io   = (const float*)d_in[23];
  const float* b_io   = (const float*)d_in[24];
  const float* w_co   = (const float*)d_in[25];
  const float* b_co   = (const float*)d_in[26];
  const float* fn_i_g = (const float*)d_in[27];
  const float* fn_i_b = (const float*)d_in[28];
  const float* fn_c_g = (const float*)d_in[29];
  const float* fn_c_b = (const float*)d_in[30];
  const float* iff_w1 = (const float*)d_in[31];
  const float* iff_b1 = (const float*)d_in[32];
  const float* iff_w2 = (const float*)d_in[33];
  const float* iff_b2 = (const float*)d_in[34];
  const float* cff_w1 = (const float*)d_in[35];
  const float* cff_b1 = (const float*)d_in[36];
  const float* cff_w2 = (const float*)d_in[37];
  const float* cff_b2 = (const float*)d_in[38];

  // ---- workspace carve (~121 MB) ----
  char* ws = (char*)d_ws;
  size_t off = 0;
  auto alloc = [&](size_t elems, size_t esz) -> void* {
    void* p = ws + off;
    off += ((elems * esz) + 255) & ~(size_t)255;
    return p;
  };
  u16* wqkvT[2]; u16* woT[2]; u16* ff1T[2]; u16* ff2T[2];
  for (int i = 0; i < 2; i++) wqkvT[i] = (u16*)alloc((size_t)3*D*D, 2);
  for (int i = 0; i < 2; i++) woT[i]   = (u16*)alloc((size_t)D*D, 2);
  for (int i = 0; i < 2; i++) ff1T[i]  = (u16*)alloc((size_t)FF*D, 2);
  for (int i = 0; i < 2; i++) ff2T[i]  = (u16*)alloc((size_t)D*FF, 2);
  u16* wiqkvT = (u16*)alloc((size_t)3*D*D, 2);   // fused [iq|ik|iv] as [2304][768]
  u16* wcqkvT = (u16*)alloc((size_t)3*D*D, 2);   // fused [cq|ck|cv]
  u16* wioT = (u16*)alloc((size_t)D*D, 2); u16* wcoT = (u16*)alloc((size_t)D*D, 2);
  u16* iff1T = (u16*)alloc((size_t)FF*D, 2); u16* iff2T = (u16*)alloc((size_t)D*FF, 2);
  u16* cff1T = (u16*)alloc((size_t)FF*D, 2); u16* cff2T = (u16*)alloc((size_t)D*FF, 2);

  float* img_f = (float*)alloc((size_t)RI*D, 4);   // fp32 residual streams
  float* cli_f = (float*)alloc((size_t)RC*D, 4);
  u16* xn_i = (u16*)alloc((size_t)RI*D, 2);
  u16* xn_c = (u16*)alloc((size_t)RC*D, 2);
  // shared region: {qkvb | cqkv} (projections) or {h1} (FFN hidden)
  u16* region = (u16*)alloc((size_t)RI*FF, 2);   // RI*FF > RI*3D + RC*3D
  u16* qkvb = region;
  u16* cqkv = region + (size_t)RI*3*D;
  u16* h1   = region;
  u16* ao_i = (u16*)alloc((size_t)RI*D, 2);      // attention outputs (bf16)
  u16* ao_c = (u16*)alloc((size_t)RC*D, 2);
  u16* vT_i = (u16*)alloc((size_t)B*D*NI, 2);    // pre-transposed V, img stream
  u16* vT_c = (u16*)alloc((size_t)B*D*NC, 2);    // pre-transposed V, clinic stream
  (void)ws_size; (void)in_sizes; (void)n_in; (void)out_size;

  auto T = [&](const float* in_, u16* out_, int R, int C){
    transpose_kernel<<<dim3(C/64, R/64), dim3(64, 4), 0, stream>>>(in_, out_, R, C);
  };
  auto TV = [&](const u16* in_, u16* out_, int N, int LD, int coff){
    transpose_v_kernel<<<dim3(D/64, N/64, B), dim3(64, 4), 0, stream>>>(in_, out_, N, LD, coff);
  };
  auto G0 = [&](const u16* A, const u16* Bt, u16* out_, int M, int N, int K){
    gemm_bt<0,1><<<dim3(N/128, M/128), 256, 0, stream>>>(A, Bt, nullptr, out_, nullptr, M, N, K);
  };
  auto G1 = [&](const u16* A, const u16* Bt, const float* bias, u16* out_, int M, int N, int K){
    gemm_bt<1,1><<<dim3(N/128, M/128), 256, 0, stream>>>(A, Bt, bias, out_, nullptr, M, N, K);
  };
  auto G2 = [&](const u16* A, const u16* Bt, const float* bias, float* resid, int M, int N, int K, int splitk){
    if (splitk == 4)
      gemm_bt<2,4><<<dim3(N/128, M/128, 4), 256, 0, stream>>>(A, Bt, bias, nullptr, resid, M, N, K);
    else if (splitk == 2)
      gemm_bt<2,2><<<dim3(N/128, M/128, 2), 256, 0, stream>>>(A, Bt, bias, nullptr, resid, M, N, K);
    else
      gemm_bt<2,1><<<dim3(N/128, M/128, 1), 256, 0, stream>>>(A, Bt, bias, nullptr, resid, M, N, K);
  };
  auto ATT = [&](const u16* Q, const u16* K_, const u16* vTp, u16* O,
                 int Nq, int Nkv, int LDq, int LDk, float w_, int acc_){
    attn_zero_kernel<<<dim3(Nq/64, H, B), 256, 0, stream>>>(Q, K_, vTp, O, Nq, Nkv, LDq, LDk, w_, acc_);
  };
  auto CP = [&](const float* in_, float* out_, long n){
    copy_f32<<<1024, 256, 0, stream>>>(in_, out_, n / 4);
  };

  // ---- weight pre-transposes (K x N fp32 -> N x K bf16) ----
  for (int li = 0; li < L; li++){
    T(w_qkv + (size_t)li*D*3*D, wqkvT[li], D, 3*D);
    T(w_o   + (size_t)li*D*D,   woT[li],   D, D);
    T(w_ff1 + (size_t)li*D*FF,  ff1T[li],  D, FF);
    T(w_ff2 + (size_t)li*FF*D,  ff2T[li],  FF, D);
  }
  T(w_iq, wiqkvT,              D, D);
  T(w_ik, wiqkvT + (size_t)D*D,   D, D);
  T(w_iv, wiqkvT + (size_t)2*D*D, D, D);
  T(w_cq, wcqkvT,              D, D);
  T(w_ck, wcqkvT + (size_t)D*D,   D, D);
  T(w_cv, wcqkvT + (size_t)2*D*D, D, D);
  T(w_io, wioT, D, D); T(w_co, wcoT, D, D);
  T(iff_w1, iff1T, D, FF); T(iff_w2, iff2T, FF, D);
  T(cff_w1, cff1T, D, FF); T(cff_w2, cff2T, FF, D);

  // ---- fp32 residual streams ----
  CP(img,    img_f, (long)RI*D);
  CP(clinic, cli_f, (long)RC*D);

  // ---- transformer stack ----
  for (int li = 0; li < L; li++){
    ln_kernel<<<RI, 256, 0, stream>>>(img_f, ln1_g + li*D, ln1_b + li*D, xn_i);
    G0(xn_i, wqkvT[li], qkvb, RI, 3*D, D);
    TV(qkvb, vT_i, NI, 3*D, 2*D);                      // V slice -> [b][768][NI]
    ATT(qkvb, qkvb + D, vT_i, ao_i, NI, NI, 3*D, 3*D, 1.0f, 0);
    G2(ao_i, woT[li], b_o + li*D, img_f, RI, D, D, 2);
    ln_kernel<<<RI, 256, 0, stream>>>(img_f, ln2_g + li*D, ln2_b + li*D, xn_i);
    G1(xn_i, ff1T[li], b_ff1 + li*FF, h1, RI, FF, D);
    G2(h1, ff2T[li], b_ff2 + li*D, img_f, RI, D, FF, 2);
  }

  // ---- cross block ----
  ln_kernel<<<RI, 256, 0, stream>>>(img_f, cn_i_g, cn_i_b, xn_i);
  ln_kernel<<<RC, 256, 0, stream>>>(cli_f, cn_c_g, cn_c_b, xn_c);
  u16* iqkv = qkvb;   // [RI][3D]: iq | ik | iv
  u16* cqk  = cqkv;   // [RC][3D]: cq | ck | cv
  G0(xn_i, wiqkvT, iqkv, RI, 3*D, D);
  G0(xn_c, wcqkvT, cqk,  RC, 3*D, D);
  TV(iqkv, vT_i, NI, 3*D, 2*D);
  TV(cqk,  vT_c, NC, 3*D, 2*D);

  ATT(iqkv, cqk + D,  vT_c, ao_i, NI, NC, 3*D, 3*D, 0.5f, 0);
  ATT(iqkv, iqkv + D, vT_i, ao_i, NI, NI, 3*D, 3*D, 0.5f, 1);
  ATT(cqk,  iqkv + D, vT_i, ao_c, NC, NI, 3*D, 3*D, 0.5f, 0);
  ATT(cqk,  cqk + D,  vT_c, ao_c, NC, NC, 3*D, 3*D, 0.5f, 1);

  G2(ao_i, wioT, b_io, img_f, RI, D, D, 2);
  G2(ao_c, wcoT, b_co, cli_f, RC, D, D, 4);

  ln_kernel<<<RI, 256, 0, stream>>>(img_f, fn_i_g, fn_i_b, xn_i);
  G1(xn_i, iff1T, iff_b1, h1, RI, FF, D);
  G2(h1, iff2T, iff_b2, img_f, RI, D, FF, 2);

  ln_kernel<<<RC, 256, 0, stream>>>(cli_f, fn_c_g, fn_c_b, xn_c);
  G1(xn_c, cff1T, cff_b1, h1, RC, FF, D);
  G2(h1, cff2T, cff_b2, cli_f, RC, D, FF, 4);

  // ---- emit fp32 outputs (img then clinic, flat) ----
  CP(img_f, (float*)d_out,                (long)RI*D);
  CP(cli_f, (float*)d_out + (size_t)RI*D, (long)RC*D);
}